// Round 11
// baseline (1176.579 us; speedup 1.0000x reference)
//
#include <hip/hip_runtime.h>
#include <cmath>

typedef float v2f __attribute__((ext_vector_type(2)));

#define GI_STRIDE (258*192)            // one gi table: 258 tokens x 192 gate-rows
#define FILM_OFF  (2*GI_STRIDE)        // 99072 floats
#define TOTAL_PRE (FILM_OFF + 256*256) // 164608 floats

#define B_TOT   1024
#define L_MAX   256
#define SOS_TOK 257
#define EOS_TOK 256

// pin a value in a VGPR (scalar/v2f only; float4 fails to compile)
#define KEEPF(x) asm volatile("" : "+v"(x))

// v_pk_fma_f32 with op_sel broadcast of one 32-bit half of x (a v2f pair)
#define PK_LO(acc, w, x) asm("v_pk_fma_f32 %0, %1, %2, %0 op_sel:[0,0,0] op_sel_hi:[1,0,1]" : "+v"(acc) : "v"(w), "v"(x))
#define PK_HI(acc, w, x) asm("v_pk_fma_f32 %0, %1, %2, %0 op_sel:[0,1,0] op_sel_hi:[1,1,1]" : "+v"(acc) : "v"(w), "v"(x))

// DPP helpers (VALU pipe)
#define DPPI(old, src, ctrl, rmask) __builtin_amdgcn_update_dpp(old, src, ctrl, rmask, 0xF, false)

// argmax (value, smallest index on ties) combine stage
#define AMAX_STAGE(ctrl, rmask) do { \
    const int   _vi = __builtin_bit_cast(int, mv); \
    const float _ov = __builtin_bit_cast(float, DPPI(_vi, _vi, ctrl, rmask)); \
    const int   _oi = DPPI(mi, mi, ctrl, rmask); \
    if (_ov > mv || (_ov == mv && _oi < mi)) { mv = _ov; mi = _oi; } \
} while (0)

// sum combine stage (disabled source lanes contribute 0 via old=0)
#define SUM_STAGE(s, ctrl, rmask) do { \
    (s) += __builtin_bit_cast(float, DPPI(0, __builtin_bit_cast(int, (s)), ctrl, rmask)); \
} while (0)

// full 64-lane reduce: row prefix (shr 1,2,4,8) then cross-row bcast; lane 63
#define AMAX64() do { \
    AMAX_STAGE(0x111, 0xF); AMAX_STAGE(0x112, 0xF); \
    AMAX_STAGE(0x114, 0xF); AMAX_STAGE(0x118, 0xF); \
    AMAX_STAGE(0x142, 0xA); AMAX_STAGE(0x143, 0xC); \
} while (0)
#define SUM64(s) do { \
    SUM_STAGE(s, 0x111, 0xF); SUM_STAGE(s, 0x112, 0xF); \
    SUM_STAGE(s, 0x114, 0xF); SUM_STAGE(s, 0x118, 0xF); \
    SUM_STAGE(s, 0x142, 0xA); SUM_STAGE(s, 0x143, 0xC); \
} while (0)
// 16-lane (row) sum: total lands in lane 15 of each row
#define SUM16(s) do { \
    SUM_STAGE(s, 0x111, 0xF); SUM_STAGE(s, 0x112, 0xF); \
    SUM_STAGE(s, 0x114, 0xF); SUM_STAGE(s, 0x118, 0xF); \
} while (0)

// ---------------------------------------------------------------------------
// Prologue: gi tables (token_embed @ w_ih.T + b_ih) and FiLM table stored as
// interleaved (gamma,beta) pairs per step.
// ---------------------------------------------------------------------------
__global__ __launch_bounds__(256) void aag_precompute(
    const float* __restrict__ token_embed,
    const float* __restrict__ step_table,
    const float* __restrict__ w_ih_f, const float* __restrict__ b_ih_f,
    const float* __restrict__ w_ih_b, const float* __restrict__ b_ih_b,
    const float* __restrict__ film_w, const float* __restrict__ film_b,
    float* __restrict__ ws)
{
    int idx = blockIdx.x * 256 + threadIdx.x;
    if (idx < FILM_OFF) {
        int m     = idx / GI_STRIDE;
        int rem   = idx - m * GI_STRIDE;
        int token = rem / 192;
        int r     = rem - token * 192;
        const float* wih = (m ? w_ih_b : w_ih_f) + r * 64;
        const float* te  = token_embed + token * 64;
        float acc = (m ? b_ih_b : b_ih_f)[r];
        #pragma unroll 8
        for (int k = 0; k < 64; ++k) acc += te[k] * wih[k];
        ws[idx] = acc;
    } else if (idx < TOTAL_PRE) {
        int q  = idx - FILM_OFF;
        int tt = q >> 8, j = q & 255;
        const float* st = step_table + tt * 16;
        const float* fw = film_w + j * 16;
        float acc = film_b[j];
        #pragma unroll
        for (int s = 0; s < 16; ++s) acc += st[s] * fw[s];
        int pos = (j < 128) ? (2 * j) : (2 * (j - 128) + 1);
        ws[FILM_OFF + tt * 256 + pos] = tanhf(acc);
    }
}

// ---------------------------------------------------------------------------
// Main persistent kernel: 512 blocks x 512 threads, 2 elems/block ->
// 2 barrier-independent blocks per CU (4 waves/SIMD): while one block
// stalls at its barrier / latency chain, the other issues matvec work.
// Role-split, reuse-2 matvecs (pk_fma), DPP softmax reductions, dec-bias
// folded into MV accumulators.
//   waves 0-3: decoder | wave 4: EOS | waves 5-7: GRU
//   even waves: argmax + gate for (e=wv>>2, m=(wv>>1)&1)
//   S-duty/output: wave 2 (e0, SIMD2), wave 4 (e1, SIMD0)
// ---------------------------------------------------------------------------
__global__ __launch_bounds__(512)
__attribute__((amdgpu_waves_per_eu(2, 4)))
void aag_decode(
    const int* __restrict__ step_ptr,
    const float* __restrict__ w_hh_f, const float* __restrict__ b_hh_f,
    const float* __restrict__ w_hh_b, const float* __restrict__ b_hh_b,
    const float* __restrict__ dec_w, const float* __restrict__ dec_b,
    const float* __restrict__ ws,
    float* __restrict__ out)
{
    __shared__ __align__(16) float hbuf[2][2][64];   // [m][e][ln] h state
    __shared__ __align__(16) float ghL[2][2][192];   // h @ w_hh.T + b_hh
    __shared__ __align__(16) float hsL[2][128];      // FiLMed concat state
    __shared__ __align__(16) float plL[2][2][264];   // [half][e][row] partials

    const int tid = threadIdx.x;
    const int wv  = tid >> 6;
    const int ln  = tid & 63;
    const int e   = wv >> 2;           // element (0/1) for P1 duties
    const int m   = (wv >> 1) & 1;     // GRU id for gate duty
    const bool gateW = (wv & 1) == 0;  // waves 0,2,4,6: argmax + gate
    const bool sduty = (wv == 2) || (wv == 4);  // SIMD2 (e0), SIMD0 (e1)

    // exponential-decay temperature, matching host double math
    float invT;
    {
        int step = step_ptr[0];
        if (step < 0) step = 0;
        double T = 0.2 + 2.3 * exp(-(0.6931471805599453 / 3000.0) * (double)step);
        if (T < 1e-6) T = 1e-6;
        invT = (float)(1.0 / T);
    }

    // ---- P2 roles ----
    const bool isDec = (tid < 256);
    const bool isEos = (tid >= 256 && tid < 272);
    const bool isGru = (tid >= 320);
    const int  dh    = tid >> 7;          // decoder half (waves 0-1: 0, 2-3: 1)
    const int  dq    = tid & 127;         // decoder row-pair index
    const int  gj    = tid - 320;
    const int  gm    = (gj >= 96) ? 1 : 0;
    const int  gp    = gj - 96 * gm;      // gru row-pair index
    const int  ec    = tid - 256;         // eos chunk index

    // ---- persistent weights ----
    v2f wreg[64];
    #pragma unroll
    for (int j = 0; j < 64; ++j) wreg[j] = (v2f){0.f, 0.f};
    v2f bias2 = {0.f, 0.f};   // gru: b_hh pair | dec dh==0: dec_b pair | eos: {dec_b[256],0}
    if (isDec) {
        const float* dw = dec_w + (2 * dq) * 128 + dh * 64;
        #pragma unroll
        for (int k = 0; k < 64; ++k) wreg[k] = (v2f){dw[k], dw[128 + k]};
        if (dh == 0) bias2 = (v2f){dec_b[2 * dq], dec_b[2 * dq + 1]};
    } else if (isGru) {
        const float* whh = (gm ? w_hh_b : w_hh_f) + (2 * gp) * 64;
        #pragma unroll
        for (int k = 0; k < 64; ++k) wreg[k] = (v2f){whh[k], whh[64 + k]};
        const float* bhh = (gm ? b_hh_b : b_hh_f) + 2 * gp;
        bias2 = (v2f){bhh[0], bhh[1]};
    } else if (isEos) {
        const float* p = dec_w + 256 * 128 + ec * 8;
        #pragma unroll
        for (int k = 0; k < 4; ++k) wreg[k] = (v2f){p[2 * k], p[2 * k + 1]};
        bias2 = (v2f){dec_b[256], 0.f};
    }
    #pragma unroll
    for (int j = 0; j < 64; ++j) KEEPF(wreg[j]);
    KEEPF(bias2);

    // ---- init ----
    if (tid < 256) ((float*)hbuf)[tid] = 0.f;        // 2*2*64 = 256 floats
    if (isGru) {                                     // gh(0) = bias (h(-1)=0)
        #pragma unroll
        for (int e2 = 0; e2 < 2; ++e2)
            *(v2f*)&ghL[gm][e2][2 * gp] = bias2;
    }

    // per-wave register state (argmax waves only; replicated, deterministic)
    bool s0m = false, s1m = false, s2m = false, s3m = false, s4m = false;
    bool done = false;

    // prefetch film(0) and gi(SOS) (gate waves)
    const float* filmT = ws + FILM_OFF;
    const float* giT   = ws + m * GI_STRIDE;
    float ga, be;
    {
        const float2 f = *(const float2*)&filmT[(m * 64 + ln) * 2];
        ga = f.x; be = f.y;
    }
    float gi_r, gi_z, gi_n;
    {
        const float* gp2 = giT + SOS_TOK * 192;
        gi_r = gp2[ln]; gi_z = gp2[64 + ln]; gi_n = gp2[128 + ln];
    }

    const int b0 = blockIdx.x * 2;
    float* __restrict__ out_act = out;
    float* __restrict__ out_lp  = out + B_TOT * L_MAX;
    float* __restrict__ out_val = out + 2 * B_TOT * L_MAX;

    __syncthreads();   // ghL / hbuf init visible

    for (int t = 0; t <= L_MAX; ++t) {
        // keep weights resident
        #pragma unroll
        for (int j = 0; j < 64; ++j) KEEPF(wreg[j]);

        // ================= P1: softmax(t-1) + gate(t) =================
        // gate operand reads issued first (latency hides under DPP chain)
        float hr = 0.f, hz = 0.f, hn = 0.f, hp = 0.f;
        if (gateW && t < L_MAX) {
            hr = ghL[m][e][ln];
            hz = ghL[m][e][64 + ln];
            hn = ghL[m][e][128 + ln];
            hp = hbuf[m][e][ln];
        }
        if (gateW && t > 0) {
            // dec_b already folded into plL via MV accumulator init
            const float u0 = plL[0][e][ln]       + plL[1][e][ln];
            const float u1 = plL[0][e][64 + ln]  + plL[1][e][64 + ln];
            const float u2 = plL[0][e][128 + ln] + plL[1][e][128 + ln];
            const float u3 = plL[0][e][192 + ln] + plL[1][e][192 + ln];
            float mv = s0m ? -INFINITY : u0;
            int   mi = ln;
            { const float v = s1m ? -INFINITY : u1; if (v > mv) { mv = v; mi = 64 + ln; } }
            { const float v = s2m ? -INFINITY : u2; if (v > mv) { mv = v; mi = 128 + ln; } }
            { const float v = s3m ? -INFINITY : u3; if (v > mv) { mv = v; mi = 192 + ln; } }
            float u4 = 0.f;
            if (ln == 0) {
                u4 = plL[0][e][256];
                const float v = s4m ? -INFINITY : u4;
                if (v > mv) { mv = v; mi = 256; }
            }
            // DPP argmax reduce (max value, smallest index on ties) -> lane 63
            AMAX64();
            const int   a   = __builtin_amdgcn_readlane(mi, 63);
            const float mvU = __builtin_bit_cast(float,
                                __builtin_amdgcn_readlane(__builtin_bit_cast(int, mv), 63));
            // gi loads for gate(t) ASAP (L2 latency hides under exp sum)
            {
                const float* gp2 = giT + a * 192;
                gi_r = gp2[ln]; gi_z = gp2[64 + ln]; gi_n = gp2[128 + ln];
            }
            // softmax denominator (feeds lp only): one wave per element
            if (sduty) {
                float S = 0.f;
                if (!s0m) S += __expf((u0 - mvU) * invT);
                if (!s1m) S += __expf((u1 - mvU) * invT);
                if (!s2m) S += __expf((u2 - mvU) * invT);
                if (!s3m) S += __expf((u3 - mvU) * invT);
                if (ln == 0 && !s4m) S += __expf((u4 - mvU) * invT);
                SUM64(S);
                const float Su = __builtin_bit_cast(float,
                                    __builtin_amdgcn_readlane(__builtin_bit_cast(int, S), 63));
                if (ln == 0) {
                    const int b = b0 + e;
                    out_act[b * L_MAX + (t - 1)] = (float)a;
                    out_lp [b * L_MAX + (t - 1)] = done ? 0.f : -__logf(Su);
                    out_val[b * L_MAX + (t - 1)] = done ? 0.f : 1.f;
                }
            }
            // state update (replicated consistently per argmax wave)
            if (a == EOS_TOK) done = true;
            if ((a & 63) == ln) {
                if (a < 64) s0m = true; else if (a < 128) s1m = true;
                else if (a < 192) s2m = true; else if (a < 256) s3m = true;
                else s4m = true;
            }
        }
        if (t == L_MAX) break;

        // ---- gate(t): wave (e, m), lane ln updates one hidden unit ----
        // (libm expf/tanhf: feeds the h recurrence -> keep precise)
        if (gateW) {
            const float r  = 1.f / (1.f + expf(-(gi_r + hr)));
            const float z  = 1.f / (1.f + expf(-(gi_z + hz)));
            const float n  = tanhf(gi_n + r * hn);
            const float h2 = (1.f - z) * n + z * hp;
            hbuf[m][e][ln] = h2;
            hsL[e][m * 64 + ln] = h2 * (1.f + ga) + be;
        }
        __syncthreads();   // B1: hbuf(t), hsL(t) ready

        // ================= P2: matvecs (reuse-2, pk_fma) ===================
        // film prefetch for t+1 (gate waves)
        if (gateW) {
            const int tn = (t + 1 < L_MAX) ? t + 1 : L_MAX - 1;
            const float2 f = *(const float2*)&filmT[tn * 256 + (m * 64 + ln) * 2];
            ga = f.x; be = f.y;
        }
        if (isDec) {
            v2f a0 = bias2, a1 = bias2;   // dh==0: dec_b pair; dh==1: 0
            const int hb = dh * 64;
            #pragma unroll
            for (int jj = 0; jj < 16; ++jj) {
                const float4 x0 = *(const float4*)&hsL[0][hb + 4 * jj];
                const float4 x1 = *(const float4*)&hsL[1][hb + 4 * jj];
                const v2f* x0v = (const v2f*)&x0;
                const v2f* x1v = (const v2f*)&x1;
                const v2f w0 = wreg[4*jj], w1 = wreg[4*jj+1], w2 = wreg[4*jj+2], w3 = wreg[4*jj+3];
                PK_LO(a0, w0, x0v[0]); PK_HI(a0, w1, x0v[0]);
                PK_LO(a0, w2, x0v[1]); PK_HI(a0, w3, x0v[1]);
                PK_LO(a1, w0, x1v[0]); PK_HI(a1, w1, x1v[0]);
                PK_LO(a1, w2, x1v[1]); PK_HI(a1, w3, x1v[1]);
            }
            *(v2f*)&plL[dh][0][2 * dq] = a0;
            *(v2f*)&plL[dh][1][2 * dq] = a1;
        } else if (isGru) {
            v2f a0 = bias2, a1 = bias2;
            #pragma unroll
            for (int jj = 0; jj < 16; ++jj) {
                const float4 x0 = *(const float4*)&hbuf[gm][0][4 * jj];
                const float4 x1 = *(const float4*)&hbuf[gm][1][4 * jj];
                const v2f* x0v = (const v2f*)&x0;
                const v2f* x1v = (const v2f*)&x1;
                const v2f w0 = wreg[4*jj], w1 = wreg[4*jj+1], w2 = wreg[4*jj+2], w3 = wreg[4*jj+3];
                PK_LO(a0, w0, x0v[0]); PK_HI(a0, w1, x0v[0]);
                PK_LO(a0, w2, x0v[1]); PK_HI(a0, w3, x0v[1]);
                PK_LO(a1, w0, x1v[0]); PK_HI(a1, w1, x1v[0]);
                PK_LO(a1, w2, x1v[1]); PK_HI(a1, w3, x1v[1]);
            }
            *(v2f*)&ghL[gm][0][2 * gp] = a0;
            *(v2f*)&ghL[gm][1][2 * gp] = a1;
        } else if (isEos) {
            float t0, t1;
            {
                const float4 p0 = *(const float4*)&hsL[0][8 * ec];
                const float4 p1 = *(const float4*)&hsL[0][8 * ec + 4];
                t0 = p0.x*wreg[0].x + p0.y*wreg[0].y + p0.z*wreg[1].x + p0.w*wreg[1].y
                   + p1.x*wreg[2].x + p1.y*wreg[2].y + p1.z*wreg[3].x + p1.w*wreg[3].y;
            }
            {
                const float4 p0 = *(const float4*)&hsL[1][8 * ec];
                const float4 p1 = *(const float4*)&hsL[1][8 * ec + 4];
                t1 = p0.x*wreg[0].x + p0.y*wreg[0].y + p0.z*wreg[1].x + p0.w*wreg[1].y
                   + p1.x*wreg[2].x + p1.y*wreg[2].y + p1.z*wreg[3].x + p1.w*wreg[3].y;
            }
            // 16-lane DPP row sum; totals land in lane 15 (ec == 15)
            SUM16(t0); SUM16(t1);
            if (ec == 15) {
                const float dbE = bias2.x;     // dec_b[256] folded here
                plL[0][0][256] = t0 + dbE;
                plL[0][1][256] = t1 + dbE;
            }
        }
        __syncthreads();   // B2: plL(t), ghL(t+1) ready
    }
}

extern "C" void kernel_launch(void* const* d_in, const int* in_sizes, int n_in,
                              void* d_out, int out_size, void* d_ws, size_t ws_size,
                              hipStream_t stream)
{
    const int*   step        = (const int*)  d_in[0];
    const float* token_embed = (const float*)d_in[2];
    const float* step_table  = (const float*)d_in[3];
    const float* w_ih_f = (const float*)d_in[4];
    const float* w_hh_f = (const float*)d_in[5];
    const float* b_ih_f = (const float*)d_in[6];
    const float* b_hh_f = (const float*)d_in[7];
    const float* w_ih_b = (const float*)d_in[8];
    const float* w_hh_b = (const float*)d_in[9];
    const float* b_ih_b = (const float*)d_in[10];
    const float* b_hh_b = (const float*)d_in[11];
    const float* film_w = (const float*)d_in[12];
    const float* film_b = (const float*)d_in[13];
    const float* dec_w  = (const float*)d_in[14];
    const float* dec_b  = (const float*)d_in[15];
    float* ws   = (float*)d_ws;
    float* outp = (float*)d_out;

    aag_precompute<<<TOTAL_PRE / 256, 256, 0, stream>>>(
        token_embed, step_table, w_ih_f, b_ih_f, w_ih_b, b_ih_b,
        film_w, film_b, ws);
    aag_decode<<<512, 512, 0, stream>>>(
        step, w_hh_f, b_hh_f, w_hh_b, b_hh_b, dec_w, dec_b, ws, outp);
}

// Round 12
// 688.864 us; speedup vs baseline: 1.7080x; 1.7080x over previous
//
#include <hip/hip_runtime.h>
#include <cmath>

typedef float v2f __attribute__((ext_vector_type(2)));

#define GI_STRIDE (258*192)            // one gi table: 258 tokens x 192 gate-rows
#define FILM_OFF  (2*GI_STRIDE)        // 99072 floats
#define TOTAL_PRE (FILM_OFF + 256*256) // 164608 floats

#define B_TOT   1024
#define L_MAX   256
#define SOS_TOK 257
#define EOS_TOK 256

// pin a value in a VGPR (scalar/v2f only; float4 fails to compile)
#define KEEPF(x) asm volatile("" : "+v"(x))

// v_pk_fma_f32 with op_sel broadcast of one 32-bit half of x (a v2f pair)
#define PK_LO(acc, w, x) asm("v_pk_fma_f32 %0, %1, %2, %0 op_sel:[0,0,0] op_sel_hi:[1,0,1]" : "+v"(acc) : "v"(w), "v"(x))
#define PK_HI(acc, w, x) asm("v_pk_fma_f32 %0, %1, %2, %0 op_sel:[0,1,0] op_sel_hi:[1,1,1]" : "+v"(acc) : "v"(w), "v"(x))

// DPP helpers (VALU pipe)
#define DPPI(old, src, ctrl, rmask) __builtin_amdgcn_update_dpp(old, src, ctrl, rmask, 0xF, false)

// argmax (value, smallest index on ties) combine stage
#define AMAX_STAGE(ctrl, rmask) do { \
    const int   _vi = __builtin_bit_cast(int, mv); \
    const float _ov = __builtin_bit_cast(float, DPPI(_vi, _vi, ctrl, rmask)); \
    const int   _oi = DPPI(mi, mi, ctrl, rmask); \
    if (_ov > mv || (_ov == mv && _oi < mi)) { mv = _ov; mi = _oi; } \
} while (0)

// sum combine stage (disabled source lanes contribute 0 via old=0)
#define SUM_STAGE(s, ctrl, rmask) do { \
    (s) += __builtin_bit_cast(float, DPPI(0, __builtin_bit_cast(int, (s)), ctrl, rmask)); \
} while (0)

// full 64-lane reduce: row prefix (shr 1,2,4,8) then cross-row bcast; lane 63
#define AMAX64() do { \
    AMAX_STAGE(0x111, 0xF); AMAX_STAGE(0x112, 0xF); \
    AMAX_STAGE(0x114, 0xF); AMAX_STAGE(0x118, 0xF); \
    AMAX_STAGE(0x142, 0xA); AMAX_STAGE(0x143, 0xC); \
} while (0)
#define SUM64(s) do { \
    SUM_STAGE(s, 0x111, 0xF); SUM_STAGE(s, 0x112, 0xF); \
    SUM_STAGE(s, 0x114, 0xF); SUM_STAGE(s, 0x118, 0xF); \
    SUM_STAGE(s, 0x142, 0xA); SUM_STAGE(s, 0x143, 0xC); \
} while (0)
// 16-lane (row) sum: total lands in lane 15 of each row
#define SUM16(s) do { \
    SUM_STAGE(s, 0x111, 0xF); SUM_STAGE(s, 0x112, 0xF); \
    SUM_STAGE(s, 0x114, 0xF); SUM_STAGE(s, 0x118, 0xF); \
} while (0)

// ---------------------------------------------------------------------------
// Prologue: gi tables (token_embed @ w_ih.T + b_ih) and FiLM table stored as
// interleaved (gamma,beta) pairs per step.
// ---------------------------------------------------------------------------
__global__ __launch_bounds__(256) void aag_precompute(
    const float* __restrict__ token_embed,
    const float* __restrict__ step_table,
    const float* __restrict__ w_ih_f, const float* __restrict__ b_ih_f,
    const float* __restrict__ w_ih_b, const float* __restrict__ b_ih_b,
    const float* __restrict__ film_w, const float* __restrict__ film_b,
    float* __restrict__ ws)
{
    int idx = blockIdx.x * 256 + threadIdx.x;
    if (idx < FILM_OFF) {
        int m     = idx / GI_STRIDE;
        int rem   = idx - m * GI_STRIDE;
        int token = rem / 192;
        int r     = rem - token * 192;
        const float* wih = (m ? w_ih_b : w_ih_f) + r * 64;
        const float* te  = token_embed + token * 64;
        float acc = (m ? b_ih_b : b_ih_f)[r];
        #pragma unroll 8
        for (int k = 0; k < 64; ++k) acc += te[k] * wih[k];
        ws[idx] = acc;
    } else if (idx < TOTAL_PRE) {
        int q  = idx - FILM_OFF;
        int tt = q >> 8, j = q & 255;
        const float* st = step_table + tt * 16;
        const float* fw = film_w + j * 16;
        float acc = film_b[j];
        #pragma unroll
        for (int s = 0; s < 16; ++s) acc += st[s] * fw[s];
        int pos = (j < 128) ? (2 * j) : (2 * (j - 128) + 1);
        ws[FILM_OFF + tt * 256 + pos] = tanhf(acc);
    }
}

// ---------------------------------------------------------------------------
// Main persistent kernel: 256 blocks x 512 threads, 4 elems/block.
// (R11 lesson: register file caps occupancy at 8 waves/CU; this shape is
// the co-residency optimum.) Role-split, reuse-2 matvecs (pk_fma), DPP
// softmax reductions, dec-bias folded into MV accumulators, one
// lp-denominator wave per SIMD (waves 0,3,5,6), fast-exp gate math.
// ---------------------------------------------------------------------------
__global__ __launch_bounds__(512)
__attribute__((amdgpu_waves_per_eu(1, 2)))
void aag_decode(
    const int* __restrict__ step_ptr,
    const float* __restrict__ w_hh_f, const float* __restrict__ b_hh_f,
    const float* __restrict__ w_hh_b, const float* __restrict__ b_hh_b,
    const float* __restrict__ dec_w, const float* __restrict__ dec_b,
    const float* __restrict__ ws,
    float* __restrict__ out)
{
    __shared__ __align__(16) float hbuf[2][4][64];   // h state (pre-FiLM)
    __shared__ __align__(16) float ghL[2][4][192];   // h @ w_hh.T + b_hh
    __shared__ __align__(16) float hsL[4][128];      // FiLMed concat state
    __shared__ __align__(16) float plL[2][4][264];   // [half][e][row] partials

    const int tid = threadIdx.x;
    const int wv  = tid >> 6;
    const int ln  = tid & 63;
    const int e   = wv >> 1;      // softmax element for this wave
    const int m   = wv & 1;       // gate-phase GRU id for this wave
    // S-duty: exactly one wave per SIMD (wave i lives on SIMD i%4):
    // waves {0,3,5,6} cover e = {0,1,2,3} on SIMDs {0,3,1,2}
    const bool sduty = (wv == 0) || (wv == 3) || (wv == 5) || (wv == 6);

    // exponential-decay temperature, matching host double math
    float invT;
    {
        int step = step_ptr[0];
        if (step < 0) step = 0;
        double T = 0.2 + 2.3 * exp(-(0.6931471805599453 / 3000.0) * (double)step);
        if (T < 1e-6) T = 1e-6;
        invT = (float)(1.0 / T);
    }

    // ---- roles ----
    const bool isDec = (tid < 256);
    const bool isEos = (tid >= 256 && tid < 272);
    const bool isGru = (tid >= 320);
    const int  dh    = tid >> 7;          // decoder half (waves 0-1: 0, 2-3: 1)
    const int  dq    = tid & 127;         // decoder row-pair index
    const int  gj    = tid - 320;
    const int  gm    = (gj >= 96) ? 1 : 0;
    const int  gp    = gj - 96 * gm;      // gru row-pair index
    const int  ec    = tid - 256;         // eos chunk index

    // ---- persistent weights ----
    v2f wreg[64];
    #pragma unroll
    for (int j = 0; j < 64; ++j) wreg[j] = (v2f){0.f, 0.f};
    v2f bias2 = {0.f, 0.f};   // gru: b_hh pair | dec dh==0: dec_b pair | eos: {dec_b[256],0}
    if (isDec) {
        const float* dw = dec_w + (2 * dq) * 128 + dh * 64;
        #pragma unroll
        for (int k = 0; k < 64; ++k) wreg[k] = (v2f){dw[k], dw[128 + k]};
        if (dh == 0) bias2 = (v2f){dec_b[2 * dq], dec_b[2 * dq + 1]};
    } else if (isGru) {
        const float* whh = (gm ? w_hh_b : w_hh_f) + (2 * gp) * 64;
        #pragma unroll
        for (int k = 0; k < 64; ++k) wreg[k] = (v2f){whh[k], whh[64 + k]};
        const float* bhh = (gm ? b_hh_b : b_hh_f) + 2 * gp;
        bias2 = (v2f){bhh[0], bhh[1]};
    } else if (isEos) {
        const float* p = dec_w + 256 * 128 + ec * 8;
        #pragma unroll
        for (int k = 0; k < 4; ++k) wreg[k] = (v2f){p[2 * k], p[2 * k + 1]};
        bias2 = (v2f){dec_b[256], 0.f};
    }
    #pragma unroll
    for (int j = 0; j < 64; ++j) KEEPF(wreg[j]);
    KEEPF(bias2);

    // ---- init ----
    ((float*)hbuf)[tid] = 0.f;                      // 512 floats = all of hbuf
    if (isGru) {                                    // gh(0) = bias (h(-1)=0)
        #pragma unroll
        for (int e2 = 0; e2 < 4; ++e2)
            *(v2f*)&ghL[gm][e2][2 * gp] = bias2;
    }

    // per-wave register state (replicated per wave, deterministic)
    bool s0m = false, s1m = false, s2m = false, s3m = false, s4m = false;
    bool done = false;

    // prefetch film(0) and gi(SOS)
    const float* filmT = ws + FILM_OFF;
    const float* giT   = ws + m * GI_STRIDE;
    float ga, be;
    {
        const float2 f = *(const float2*)&filmT[(m * 64 + ln) * 2];
        ga = f.x; be = f.y;
    }
    float gi_r, gi_z, gi_n;
    {
        const float* gp2 = giT + SOS_TOK * 192;
        gi_r = gp2[ln]; gi_z = gp2[64 + ln]; gi_n = gp2[128 + ln];
    }

    const int b0 = blockIdx.x * 4;
    float* __restrict__ out_act = out;
    float* __restrict__ out_lp  = out + B_TOT * L_MAX;
    float* __restrict__ out_val = out + 2 * B_TOT * L_MAX;

    __syncthreads();   // ghL / hbuf init visible

    for (int t = 0; t <= L_MAX; ++t) {
        // ================= P1: softmax(t-1) + gate(t) =================
        // gate operand reads issued FIRST (no dependence on argmax; their
        // LDS latency hides under the DPP chain)
        float hr = 0.f, hz = 0.f, hn = 0.f, hp = 0.f;
        if (t < L_MAX) {
            hr = ghL[m][e][ln];
            hz = ghL[m][e][64 + ln];
            hn = ghL[m][e][128 + ln];
            hp = hbuf[m][e][ln];
        }
        if (t > 0) {
            // dec_b already folded into plL via MV accumulator init
            const float u0 = plL[0][e][ln]       + plL[1][e][ln];
            const float u1 = plL[0][e][64 + ln]  + plL[1][e][64 + ln];
            const float u2 = plL[0][e][128 + ln] + plL[1][e][128 + ln];
            const float u3 = plL[0][e][192 + ln] + plL[1][e][192 + ln];
            float mv = s0m ? -INFINITY : u0;
            int   mi = ln;
            { const float v = s1m ? -INFINITY : u1; if (v > mv) { mv = v; mi = 64 + ln; } }
            { const float v = s2m ? -INFINITY : u2; if (v > mv) { mv = v; mi = 128 + ln; } }
            { const float v = s3m ? -INFINITY : u3; if (v > mv) { mv = v; mi = 192 + ln; } }
            float u4 = 0.f;
            if (ln == 0) {
                u4 = plL[0][e][256];
                const float v = s4m ? -INFINITY : u4;
                if (v > mv) { mv = v; mi = 256; }
            }
            // DPP argmax reduce (max value, smallest index on ties) -> lane 63
            AMAX64();
            const int   a   = __builtin_amdgcn_readlane(mi, 63);
            const float mvU = __builtin_bit_cast(float,
                                __builtin_amdgcn_readlane(__builtin_bit_cast(int, mv), 63));
            // gi loads for gate(t) ASAP (L2 latency hides under exp sum)
            {
                const float* gp2 = giT + a * 192;
                gi_r = gp2[ln]; gi_z = gp2[64 + ln]; gi_n = gp2[128 + ln];
            }
            // softmax denominator (feeds lp only): one wave per SIMD
            if (sduty) {
                float S = 0.f;
                if (!s0m) S += __expf((u0 - mvU) * invT);
                if (!s1m) S += __expf((u1 - mvU) * invT);
                if (!s2m) S += __expf((u2 - mvU) * invT);
                if (!s3m) S += __expf((u3 - mvU) * invT);
                if (ln == 0 && !s4m) S += __expf((u4 - mvU) * invT);
                SUM64(S);
                const float Su = __builtin_bit_cast(float,
                                    __builtin_amdgcn_readlane(__builtin_bit_cast(int, S), 63));
                if (ln == 0) {
                    const int b = b0 + e;
                    out_act[b * L_MAX + (t - 1)] = (float)a;
                    out_lp [b * L_MAX + (t - 1)] = done ? 0.f : -__logf(Su);
                    out_val[b * L_MAX + (t - 1)] = done ? 0.f : 1.f;
                }
            }
            // state update (registers, replicated consistently per wave)
            if (a == EOS_TOK) done = true;
            if ((a & 63) == ln) {
                if (a < 64) s0m = true; else if (a < 128) s1m = true;
                else if (a < 192) s2m = true; else if (a < 256) s3m = true;
                else s4m = true;
            }
        }
        if (t == L_MAX) break;

        // ---- gate(t): thread (m, e, ln) updates one hidden unit ----
        // fast-exp gate math: v_exp_f32-based sigmoid/tanh (divisions kept
        // IEEE-precise; only the exp poly changes, ~2-3 ulp). Sigmoid is
        // robust at +/-inf; tanh clamped below -20 to avoid inf-inf NaN.
        {
            const float r  = 1.f / (1.f + __expf(-(gi_r + hr)));
            const float z  = 1.f / (1.f + __expf(-(gi_z + hz)));
            const float yn = fmaxf(gi_n + r * hn, -20.f);
            const float ex = __expf(-2.f * yn);
            const float n  = (1.f - ex) / (1.f + ex);
            const float h2 = (1.f - z) * n + z * hp;
            hbuf[m][e][ln] = h2;
            hsL[e][m * 64 + ln] = h2 * (1.f + ga) + be;
        }
        __syncthreads();   // B1: hbuf(t), hsL(t) ready

        // ================= P2: matvecs (reuse-2, pk_fma) ===================
        // film prefetch for t+1
        {
            const int tn = (t + 1 < L_MAX) ? t + 1 : L_MAX - 1;
            const float2 f = *(const float2*)&filmT[tn * 256 + (m * 64 + ln) * 2];
            ga = f.x; be = f.y;
        }
        if (isDec) {
            v2f a0 = bias2, a1 = bias2, a2 = bias2, a3 = bias2;  // dh==0: dec_b pair; dh==1: 0
            const int hb = dh * 64;
            #pragma unroll
            for (int jj = 0; jj < 16; ++jj) {
                const float4 x0 = *(const float4*)&hsL[0][hb + 4 * jj];
                const float4 x1 = *(const float4*)&hsL[1][hb + 4 * jj];
                const float4 x2 = *(const float4*)&hsL[2][hb + 4 * jj];
                const float4 x3 = *(const float4*)&hsL[3][hb + 4 * jj];
                const v2f* x0v = (const v2f*)&x0;
                const v2f* x1v = (const v2f*)&x1;
                const v2f* x2v = (const v2f*)&x2;
                const v2f* x3v = (const v2f*)&x3;
                const v2f w0 = wreg[4*jj], w1 = wreg[4*jj+1], w2 = wreg[4*jj+2], w3 = wreg[4*jj+3];
                PK_LO(a0, w0, x0v[0]); PK_HI(a0, w1, x0v[0]);
                PK_LO(a0, w2, x0v[1]); PK_HI(a0, w3, x0v[1]);
                PK_LO(a1, w0, x1v[0]); PK_HI(a1, w1, x1v[0]);
                PK_LO(a1, w2, x1v[1]); PK_HI(a1, w3, x1v[1]);
                PK_LO(a2, w0, x2v[0]); PK_HI(a2, w1, x2v[0]);
                PK_LO(a2, w2, x2v[1]); PK_HI(a2, w3, x2v[1]);
                PK_LO(a3, w0, x3v[0]); PK_HI(a3, w1, x3v[0]);
                PK_LO(a3, w2, x3v[1]); PK_HI(a3, w3, x3v[1]);
            }
            *(v2f*)&plL[dh][0][2 * dq] = a0;
            *(v2f*)&plL[dh][1][2 * dq] = a1;
            *(v2f*)&plL[dh][2][2 * dq] = a2;
            *(v2f*)&plL[dh][3][2 * dq] = a3;
        } else if (isGru) {
            v2f a0 = bias2, a1 = bias2, a2 = bias2, a3 = bias2;
            #pragma unroll
            for (int jj = 0; jj < 16; ++jj) {
                const float4 x0 = *(const float4*)&hbuf[gm][0][4 * jj];
                const float4 x1 = *(const float4*)&hbuf[gm][1][4 * jj];
                const float4 x2 = *(const float4*)&hbuf[gm][2][4 * jj];
                const float4 x3 = *(const float4*)&hbuf[gm][3][4 * jj];
                const v2f* x0v = (const v2f*)&x0;
                const v2f* x1v = (const v2f*)&x1;
                const v2f* x2v = (const v2f*)&x2;
                const v2f* x3v = (const v2f*)&x3;
                const v2f w0 = wreg[4*jj], w1 = wreg[4*jj+1], w2 = wreg[4*jj+2], w3 = wreg[4*jj+3];
                PK_LO(a0, w0, x0v[0]); PK_HI(a0, w1, x0v[0]);
                PK_LO(a0, w2, x0v[1]); PK_HI(a0, w3, x0v[1]);
                PK_LO(a1, w0, x1v[0]); PK_HI(a1, w1, x1v[0]);
                PK_LO(a1, w2, x1v[1]); PK_HI(a1, w3, x1v[1]);
                PK_LO(a2, w0, x2v[0]); PK_HI(a2, w1, x2v[0]);
                PK_LO(a2, w2, x2v[1]); PK_HI(a2, w3, x2v[1]);
                PK_LO(a3, w0, x3v[0]); PK_HI(a3, w1, x3v[0]);
                PK_LO(a3, w2, x3v[1]); PK_HI(a3, w3, x3v[1]);
            }
            *(v2f*)&ghL[gm][0][2 * gp] = a0;
            *(v2f*)&ghL[gm][1][2 * gp] = a1;
            *(v2f*)&ghL[gm][2][2 * gp] = a2;
            *(v2f*)&ghL[gm][3][2 * gp] = a3;
        } else if (isEos) {
            float t0, t1, t2, t3;
            {
                const float4 p0 = *(const float4*)&hsL[0][8 * ec];
                const float4 p1 = *(const float4*)&hsL[0][8 * ec + 4];
                t0 = p0.x*wreg[0].x + p0.y*wreg[0].y + p0.z*wreg[1].x + p0.w*wreg[1].y
                   + p1.x*wreg[2].x + p1.y*wreg[2].y + p1.z*wreg[3].x + p1.w*wreg[3].y;
            }
            {
                const float4 p0 = *(const float4*)&hsL[1][8 * ec];
                const float4 p1 = *(const float4*)&hsL[1][8 * ec + 4];
                t1 = p0.x*wreg[0].x + p0.y*wreg[0].y + p0.z*wreg[1].x + p0.w*wreg[1].y
                   + p1.x*wreg[2].x + p1.y*wreg[2].y + p1.z*wreg[3].x + p1.w*wreg[3].y;
            }
            {
                const float4 p0 = *(const float4*)&hsL[2][8 * ec];
                const float4 p1 = *(const float4*)&hsL[2][8 * ec + 4];
                t2 = p0.x*wreg[0].x + p0.y*wreg[0].y + p0.z*wreg[1].x + p0.w*wreg[1].y
                   + p1.x*wreg[2].x + p1.y*wreg[2].y + p1.z*wreg[3].x + p1.w*wreg[3].y;
            }
            {
                const float4 p0 = *(const float4*)&hsL[3][8 * ec];
                const float4 p1 = *(const float4*)&hsL[3][8 * ec + 4];
                t3 = p0.x*wreg[0].x + p0.y*wreg[0].y + p0.z*wreg[1].x + p0.w*wreg[1].y
                   + p1.x*wreg[2].x + p1.y*wreg[2].y + p1.z*wreg[3].x + p1.w*wreg[3].y;
            }
            // 16-lane DPP row sum; totals land in lane 15 (ec == 15)
            SUM16(t0); SUM16(t1); SUM16(t2); SUM16(t3);
            if (ec == 15) {
                const float dbE = bias2.x;     // dec_b[256] folded here
                plL[0][0][256] = t0 + dbE; plL[0][1][256] = t1 + dbE;
                plL[0][2][256] = t2 + dbE; plL[0][3][256] = t3 + dbE;
            }
        }
        __syncthreads();   // B2: plL(t), ghL(t+1) ready
    }
}

extern "C" void kernel_launch(void* const* d_in, const int* in_sizes, int n_in,
                              void* d_out, int out_size, void* d_ws, size_t ws_size,
                              hipStream_t stream)
{
    const int*   step        = (const int*)  d_in[0];
    const float* token_embed = (const float*)d_in[2];
    const float* step_table  = (const float*)d_in[3];
    const float* w_ih_f = (const float*)d_in[4];
    const float* w_hh_f = (const float*)d_in[5];
    const float* b_ih_f = (const float*)d_in[6];
    const float* b_hh_f = (const float*)d_in[7];
    const float* w_ih_b = (const float*)d_in[8];
    const float* w_hh_b = (const float*)d_in[9];
    const float* b_ih_b = (const float*)d_in[10];
    const float* b_hh_b = (const float*)d_in[11];
    const float* film_w = (const float*)d_in[12];
    const float* film_b = (const float*)d_in[13];
    const float* dec_w  = (const float*)d_in[14];
    const float* dec_b  = (const float*)d_in[15];
    float* ws   = (float*)d_ws;
    float* outp = (float*)d_out;

    aag_precompute<<<TOTAL_PRE / 256, 256, 0, stream>>>(
        token_embed, step_table, w_ih_f, b_ih_f, w_ih_b, b_ih_b,
        film_w, film_b, ws);
    aag_decode<<<256, 512, 0, stream>>>(
        step, w_hh_f, b_hh_f, w_hh_b, b_hh_b, dec_w, dec_b, ws, outp);
}

// Round 13
// 679.805 us; speedup vs baseline: 1.7308x; 1.0133x over previous
//
#include <hip/hip_runtime.h>
#include <cmath>

typedef float v2f __attribute__((ext_vector_type(2)));

#define GI_STRIDE (258*192)            // one gi table: 258 tokens x 192 slots
#define FILM_OFF  (2*GI_STRIDE)        // 99072 floats
#define TOTAL_PRE (FILM_OFF + 256*256) // 164608 floats

#define B_TOT   1024
#define L_MAX   256
#define SOS_TOK 257
#define EOS_TOK 256

// pin a value in a VGPR (scalar/v2f only; float4 fails to compile)
#define KEEPF(x) asm volatile("" : "+v"(x))

// v_pk_fma_f32 with op_sel broadcast of one 32-bit half of x (a v2f pair)
#define PK_LO(acc, w, x) asm("v_pk_fma_f32 %0, %1, %2, %0 op_sel:[0,0,0] op_sel_hi:[1,0,1]" : "+v"(acc) : "v"(w), "v"(x))
#define PK_HI(acc, w, x) asm("v_pk_fma_f32 %0, %1, %2, %0 op_sel:[0,1,0] op_sel_hi:[1,1,1]" : "+v"(acc) : "v"(w), "v"(x))

// DPP helpers (VALU pipe)
#define DPPI(old, src, ctrl, rmask) __builtin_amdgcn_update_dpp(old, src, ctrl, rmask, 0xF, false)

// argmax (value, smallest index on ties) combine stage
#define AMAX_STAGE(ctrl, rmask) do { \
    const int   _vi = __builtin_bit_cast(int, mv); \
    const float _ov = __builtin_bit_cast(float, DPPI(_vi, _vi, ctrl, rmask)); \
    const int   _oi = DPPI(mi, mi, ctrl, rmask); \
    if (_ov > mv || (_ov == mv && _oi < mi)) { mv = _ov; mi = _oi; } \
} while (0)

// sum combine stage (disabled source lanes contribute 0 via old=0)
#define SUM_STAGE(s, ctrl, rmask) do { \
    (s) += __builtin_bit_cast(float, DPPI(0, __builtin_bit_cast(int, (s)), ctrl, rmask)); \
} while (0)

// full 64-lane reduce: row prefix (shr 1,2,4,8) then cross-row bcast; lane 63
#define AMAX64() do { \
    AMAX_STAGE(0x111, 0xF); AMAX_STAGE(0x112, 0xF); \
    AMAX_STAGE(0x114, 0xF); AMAX_STAGE(0x118, 0xF); \
    AMAX_STAGE(0x142, 0xA); AMAX_STAGE(0x143, 0xC); \
} while (0)
#define SUM64(s) do { \
    SUM_STAGE(s, 0x111, 0xF); SUM_STAGE(s, 0x112, 0xF); \
    SUM_STAGE(s, 0x114, 0xF); SUM_STAGE(s, 0x118, 0xF); \
    SUM_STAGE(s, 0x142, 0xA); SUM_STAGE(s, 0x143, 0xC); \
} while (0)
// 16-lane (row) sum: total lands in lane 15 of each row
#define SUM16(s) do { \
    SUM_STAGE(s, 0x111, 0xF); SUM_STAGE(s, 0x112, 0xF); \
    SUM_STAGE(s, 0x114, 0xF); SUM_STAGE(s, 0x118, 0xF); \
} while (0)

// ---------------------------------------------------------------------------
// Prologue: gi tables + FiLM table.
// gi layout (per m, token): slots [2*l, 2*l+1] = (r,z) gates of unit l;
// slots [128+l] = n gate of unit l. So the decode-side fetch is one aligned
// b64 (r,z) + one b32 (n) per lane instead of three scattered b32.
// ---------------------------------------------------------------------------
__global__ __launch_bounds__(256) void aag_precompute(
    const float* __restrict__ token_embed,
    const float* __restrict__ step_table,
    const float* __restrict__ w_ih_f, const float* __restrict__ b_ih_f,
    const float* __restrict__ w_ih_b, const float* __restrict__ b_ih_b,
    const float* __restrict__ film_w, const float* __restrict__ film_b,
    float* __restrict__ ws)
{
    int idx = blockIdx.x * 256 + threadIdx.x;
    if (idx < FILM_OFF) {
        int m     = idx / GI_STRIDE;
        int rem   = idx - m * GI_STRIDE;
        int token = rem / 192;
        int s     = rem - token * 192;
        // slot -> original gate row: s<128: row = (s&1)*64 + (s>>1); else row = s
        int r = (s < 128) ? ((s & 1) * 64 + (s >> 1)) : s;
        const float* wih = (m ? w_ih_b : w_ih_f) + r * 64;
        const float* te  = token_embed + token * 64;
        float acc = (m ? b_ih_b : b_ih_f)[r];
        #pragma unroll 8
        for (int k = 0; k < 64; ++k) acc += te[k] * wih[k];
        ws[idx] = acc;
    } else if (idx < TOTAL_PRE) {
        int q  = idx - FILM_OFF;
        int tt = q >> 8, j = q & 255;
        const float* st = step_table + tt * 16;
        const float* fw = film_w + j * 16;
        float acc = film_b[j];
        #pragma unroll
        for (int s = 0; s < 16; ++s) acc += st[s] * fw[s];
        int pos = (j < 128) ? (2 * j) : (2 * (j - 128) + 1);
        ws[FILM_OFF + tt * 256 + pos] = tanhf(acc);
    }
}

// ---------------------------------------------------------------------------
// Main persistent kernel: 256 blocks x 512 threads, 4 elems/block.
// Role-split, reuse-2 matvecs (pk_fma), DPP softmax reductions, dec-bias
// folded into MV accumulators, one lp-denominator wave per SIMD, fast-exp
// gate math, paired plL layout (b64 softmax reads), packed gi fetch.
// ---------------------------------------------------------------------------
__global__ __launch_bounds__(512)
__attribute__((amdgpu_waves_per_eu(1, 2)))
void aag_decode(
    const int* __restrict__ step_ptr,
    const float* __restrict__ w_hh_f, const float* __restrict__ b_hh_f,
    const float* __restrict__ w_hh_b, const float* __restrict__ b_hh_b,
    const float* __restrict__ dec_w, const float* __restrict__ dec_b,
    const float* __restrict__ ws,
    float* __restrict__ out)
{
    __shared__ __align__(16) float hbuf[2][4][64];   // h state (pre-FiLM)
    __shared__ __align__(16) float ghL[2][4][192];   // h @ w_hh.T + b_hh
    __shared__ __align__(16) float hsL[4][128];      // FiLMed concat state
    __shared__ __align__(16) float plL[4][264][2];   // [e][row][{half0,half1}]

    const int tid = threadIdx.x;
    const int wv  = tid >> 6;
    const int ln  = tid & 63;
    const int e   = wv >> 1;      // softmax element for this wave
    const int m   = wv & 1;       // gate-phase GRU id for this wave
    // S-duty: exactly one wave per SIMD (wave i lives on SIMD i%4):
    // waves {0,3,5,6} cover e = {0,1,2,3} on SIMDs {0,3,1,2}
    const bool sduty = (wv == 0) || (wv == 3) || (wv == 5) || (wv == 6);

    // exponential-decay temperature, matching host double math
    float invT;
    {
        int step = step_ptr[0];
        if (step < 0) step = 0;
        double T = 0.2 + 2.3 * exp(-(0.6931471805599453 / 3000.0) * (double)step);
        if (T < 1e-6) T = 1e-6;
        invT = (float)(1.0 / T);
    }

    // ---- roles ----
    const bool isDec = (tid < 256);
    const bool isEos = (tid >= 256 && tid < 272);
    const bool isGru = (tid >= 320);
    const int  dh    = tid >> 7;          // decoder half (waves 0-1: 0, 2-3: 1)
    const int  dq    = tid & 127;         // decoder row-pair index
    const int  gj    = tid - 320;
    const int  gm    = (gj >= 96) ? 1 : 0;
    const int  gp    = gj - 96 * gm;      // gru row-pair index
    const int  ec    = tid - 256;         // eos chunk index

    // ---- persistent weights ----
    v2f wreg[64];
    #pragma unroll
    for (int j = 0; j < 64; ++j) wreg[j] = (v2f){0.f, 0.f};
    v2f bias2 = {0.f, 0.f};   // gru: b_hh pair | dec dh==0: dec_b pair | eos: {dec_b[256],0}
    if (isDec) {
        const float* dw = dec_w + (2 * dq) * 128 + dh * 64;
        #pragma unroll
        for (int k = 0; k < 64; ++k) wreg[k] = (v2f){dw[k], dw[128 + k]};
        if (dh == 0) bias2 = (v2f){dec_b[2 * dq], dec_b[2 * dq + 1]};
    } else if (isGru) {
        const float* whh = (gm ? w_hh_b : w_hh_f) + (2 * gp) * 64;
        #pragma unroll
        for (int k = 0; k < 64; ++k) wreg[k] = (v2f){whh[k], whh[64 + k]};
        const float* bhh = (gm ? b_hh_b : b_hh_f) + 2 * gp;
        bias2 = (v2f){bhh[0], bhh[1]};
    } else if (isEos) {
        const float* p = dec_w + 256 * 128 + ec * 8;
        #pragma unroll
        for (int k = 0; k < 4; ++k) wreg[k] = (v2f){p[2 * k], p[2 * k + 1]};
        bias2 = (v2f){dec_b[256], 0.f};
    }
    #pragma unroll
    for (int j = 0; j < 64; ++j) KEEPF(wreg[j]);
    KEEPF(bias2);

    // ---- init ----
    ((float*)hbuf)[tid] = 0.f;                      // 512 floats = all of hbuf
    if (isGru) {                                    // gh(0) = bias (h(-1)=0)
        #pragma unroll
        for (int e2 = 0; e2 < 4; ++e2)
            *(v2f*)&ghL[gm][e2][2 * gp] = bias2;
    }

    // per-wave register state (replicated per wave, deterministic)
    bool s0m = false, s1m = false, s2m = false, s3m = false, s4m = false;
    bool done = false;

    // prefetch film(0) and gi(SOS) (packed layout)
    const float* filmT = ws + FILM_OFF;
    const float* giT   = ws + m * GI_STRIDE;
    float ga, be;
    {
        const float2 f = *(const float2*)&filmT[(m * 64 + ln) * 2];
        ga = f.x; be = f.y;
    }
    float gi_r, gi_z, gi_n;
    {
        const float2 rz = *(const float2*)&giT[SOS_TOK * 192 + 2 * ln];
        gi_r = rz.x; gi_z = rz.y;
        gi_n = giT[SOS_TOK * 192 + 128 + ln];
    }

    const int b0 = blockIdx.x * 4;
    float* __restrict__ out_act = out;
    float* __restrict__ out_lp  = out + B_TOT * L_MAX;
    float* __restrict__ out_val = out + 2 * B_TOT * L_MAX;

    __syncthreads();   // ghL / hbuf init visible

    for (int t = 0; t <= L_MAX; ++t) {
        // re-pin the weights each iteration (R10 best config)
        #pragma unroll
        for (int j = 0; j < 64; ++j) KEEPF(wreg[j]);

        // ================= P1: softmax(t-1) + gate(t) =================
        // gate operand reads issued FIRST (no dependence on argmax; their
        // LDS latency hides under the DPP chain)
        float hr = 0.f, hz = 0.f, hn = 0.f, hp = 0.f;
        if (t < L_MAX) {
            hr = ghL[m][e][ln];
            hz = ghL[m][e][64 + ln];
            hn = ghL[m][e][128 + ln];
            hp = hbuf[m][e][ln];
        }
        if (t > 0) {
            // paired layout: one b64 per logit quarter (dec_b pre-folded)
            const float2 q0 = *(const float2*)&plL[e][ln][0];
            const float2 q1 = *(const float2*)&plL[e][64 + ln][0];
            const float2 q2 = *(const float2*)&plL[e][128 + ln][0];
            const float2 q3 = *(const float2*)&plL[e][192 + ln][0];
            const float u0 = q0.x + q0.y;
            const float u1 = q1.x + q1.y;
            const float u2 = q2.x + q2.y;
            const float u3 = q3.x + q3.y;
            float mv = s0m ? -INFINITY : u0;
            int   mi = ln;
            { const float v = s1m ? -INFINITY : u1; if (v > mv) { mv = v; mi = 64 + ln; } }
            { const float v = s2m ? -INFINITY : u2; if (v > mv) { mv = v; mi = 128 + ln; } }
            { const float v = s3m ? -INFINITY : u3; if (v > mv) { mv = v; mi = 192 + ln; } }
            float u4 = 0.f;
            if (ln == 0) {
                u4 = plL[e][256][0];
                const float v = s4m ? -INFINITY : u4;
                if (v > mv) { mv = v; mi = 256; }
            }
            // DPP argmax reduce (max value, smallest index on ties) -> lane 63
            AMAX64();
            const int   a   = __builtin_amdgcn_readlane(mi, 63);
            const float mvU = __builtin_bit_cast(float,
                                __builtin_amdgcn_readlane(__builtin_bit_cast(int, mv), 63));
            // gi loads for gate(t): one b64 + one b32 (packed layout)
            {
                const float2 rz = *(const float2*)&giT[a * 192 + 2 * ln];
                gi_r = rz.x; gi_z = rz.y;
                gi_n = giT[a * 192 + 128 + ln];
            }
            // softmax denominator (feeds lp only): one wave per SIMD
            if (sduty) {
                float S = 0.f;
                if (!s0m) S += __expf((u0 - mvU) * invT);
                if (!s1m) S += __expf((u1 - mvU) * invT);
                if (!s2m) S += __expf((u2 - mvU) * invT);
                if (!s3m) S += __expf((u3 - mvU) * invT);
                if (ln == 0 && !s4m) S += __expf((u4 - mvU) * invT);
                SUM64(S);
                const float Su = __builtin_bit_cast(float,
                                    __builtin_amdgcn_readlane(__builtin_bit_cast(int, S), 63));
                if (ln == 0) {
                    const int b = b0 + e;
                    out_act[b * L_MAX + (t - 1)] = (float)a;
                    out_lp [b * L_MAX + (t - 1)] = done ? 0.f : -__logf(Su);
                    out_val[b * L_MAX + (t - 1)] = done ? 0.f : 1.f;
                }
            }
            // state update (registers, replicated consistently per wave)
            if (a == EOS_TOK) done = true;
            if ((a & 63) == ln) {
                if (a < 64) s0m = true; else if (a < 128) s1m = true;
                else if (a < 192) s2m = true; else if (a < 256) s3m = true;
                else s4m = true;
            }
        }
        if (t == L_MAX) break;

        // ---- gate(t): thread (m, e, ln) updates one hidden unit ----
        // fast-exp gate math (validated neutral in R12, absmax 0.0)
        {
            const float r  = 1.f / (1.f + __expf(-(gi_r + hr)));
            const float z  = 1.f / (1.f + __expf(-(gi_z + hz)));
            const float yn = fmaxf(gi_n + r * hn, -20.f);
            const float ex = __expf(-2.f * yn);
            const float n  = (1.f - ex) / (1.f + ex);
            const float h2 = (1.f - z) * n + z * hp;
            hbuf[m][e][ln] = h2;
            hsL[e][m * 64 + ln] = h2 * (1.f + ga) + be;
        }
        __syncthreads();   // B1: hbuf(t), hsL(t) ready

        // ================= P2: matvecs (reuse-2, pk_fma) ===================
        // film prefetch for t+1
        {
            const int tn = (t + 1 < L_MAX) ? t + 1 : L_MAX - 1;
            const float2 f = *(const float2*)&filmT[tn * 256 + (m * 64 + ln) * 2];
            ga = f.x; be = f.y;
        }
        if (isDec) {
            v2f a0 = bias2, a1 = bias2, a2 = bias2, a3 = bias2;  // dh==0: dec_b pair; dh==1: 0
            const int hb = dh * 64;
            #pragma unroll
            for (int jj = 0; jj < 16; ++jj) {
                const float4 x0 = *(const float4*)&hsL[0][hb + 4 * jj];
                const float4 x1 = *(const float4*)&hsL[1][hb + 4 * jj];
                const float4 x2 = *(const float4*)&hsL[2][hb + 4 * jj];
                const float4 x3 = *(const float4*)&hsL[3][hb + 4 * jj];
                const v2f* x0v = (const v2f*)&x0;
                const v2f* x1v = (const v2f*)&x1;
                const v2f* x2v = (const v2f*)&x2;
                const v2f* x3v = (const v2f*)&x3;
                const v2f w0 = wreg[4*jj], w1 = wreg[4*jj+1], w2 = wreg[4*jj+2], w3 = wreg[4*jj+3];
                PK_LO(a0, w0, x0v[0]); PK_HI(a0, w1, x0v[0]);
                PK_LO(a0, w2, x0v[1]); PK_HI(a0, w3, x0v[1]);
                PK_LO(a1, w0, x1v[0]); PK_HI(a1, w1, x1v[0]);
                PK_LO(a1, w2, x1v[1]); PK_HI(a1, w3, x1v[1]);
                PK_LO(a2, w0, x2v[0]); PK_HI(a2, w1, x2v[0]);
                PK_LO(a2, w2, x2v[1]); PK_HI(a2, w3, x2v[1]);
                PK_LO(a3, w0, x3v[0]); PK_HI(a3, w1, x3v[0]);
                PK_LO(a3, w2, x3v[1]); PK_HI(a3, w3, x3v[1]);
            }
            // paired layout: component dh of rows (2dq, 2dq+1)
            plL[0][2 * dq][dh] = a0.x; plL[0][2 * dq + 1][dh] = a0.y;
            plL[1][2 * dq][dh] = a1.x; plL[1][2 * dq + 1][dh] = a1.y;
            plL[2][2 * dq][dh] = a2.x; plL[2][2 * dq + 1][dh] = a2.y;
            plL[3][2 * dq][dh] = a3.x; plL[3][2 * dq + 1][dh] = a3.y;
        } else if (isGru) {
            v2f a0 = bias2, a1 = bias2, a2 = bias2, a3 = bias2;
            #pragma unroll
            for (int jj = 0; jj < 16; ++jj) {
                const float4 x0 = *(const float4*)&hbuf[gm][0][4 * jj];
                const float4 x1 = *(const float4*)&hbuf[gm][1][4 * jj];
                const float4 x2 = *(const float4*)&hbuf[gm][2][4 * jj];
                const float4 x3 = *(const float4*)&hbuf[gm][3][4 * jj];
                const v2f* x0v = (const v2f*)&x0;
                const v2f* x1v = (const v2f*)&x1;
                const v2f* x2v = (const v2f*)&x2;
                const v2f* x3v = (const v2f*)&x3;
                const v2f w0 = wreg[4*jj], w1 = wreg[4*jj+1], w2 = wreg[4*jj+2], w3 = wreg[4*jj+3];
                PK_LO(a0, w0, x0v[0]); PK_HI(a0, w1, x0v[0]);
                PK_LO(a0, w2, x0v[1]); PK_HI(a0, w3, x0v[1]);
                PK_LO(a1, w0, x1v[0]); PK_HI(a1, w1, x1v[0]);
                PK_LO(a1, w2, x1v[1]); PK_HI(a1, w3, x1v[1]);
                PK_LO(a2, w0, x2v[0]); PK_HI(a2, w1, x2v[0]);
                PK_LO(a2, w2, x2v[1]); PK_HI(a2, w3, x2v[1]);
                PK_LO(a3, w0, x3v[0]); PK_HI(a3, w1, x3v[0]);
                PK_LO(a3, w2, x3v[1]); PK_HI(a3, w3, x3v[1]);
            }
            *(v2f*)&ghL[gm][0][2 * gp] = a0;
            *(v2f*)&ghL[gm][1][2 * gp] = a1;
            *(v2f*)&ghL[gm][2][2 * gp] = a2;
            *(v2f*)&ghL[gm][3][2 * gp] = a3;
        } else if (isEos) {
            float t0, t1, t2, t3;
            {
                const float4 p0 = *(const float4*)&hsL[0][8 * ec];
                const float4 p1 = *(const float4*)&hsL[0][8 * ec + 4];
                t0 = p0.x*wreg[0].x + p0.y*wreg[0].y + p0.z*wreg[1].x + p0.w*wreg[1].y
                   + p1.x*wreg[2].x + p1.y*wreg[2].y + p1.z*wreg[3].x + p1.w*wreg[3].y;
            }
            {
                const float4 p0 = *(const float4*)&hsL[1][8 * ec];
                const float4 p1 = *(const float4*)&hsL[1][8 * ec + 4];
                t1 = p0.x*wreg[0].x + p0.y*wreg[0].y + p0.z*wreg[1].x + p0.w*wreg[1].y
                   + p1.x*wreg[2].x + p1.y*wreg[2].y + p1.z*wreg[3].x + p1.w*wreg[3].y;
            }
            {
                const float4 p0 = *(const float4*)&hsL[2][8 * ec];
                const float4 p1 = *(const float4*)&hsL[2][8 * ec + 4];
                t2 = p0.x*wreg[0].x + p0.y*wreg[0].y + p0.z*wreg[1].x + p0.w*wreg[1].y
                   + p1.x*wreg[2].x + p1.y*wreg[2].y + p1.z*wreg[3].x + p1.w*wreg[3].y;
            }
            {
                const float4 p0 = *(const float4*)&hsL[3][8 * ec];
                const float4 p1 = *(const float4*)&hsL[3][8 * ec + 4];
                t3 = p0.x*wreg[0].x + p0.y*wreg[0].y + p0.z*wreg[1].x + p0.w*wreg[1].y
                   + p1.x*wreg[2].x + p1.y*wreg[2].y + p1.z*wreg[3].x + p1.w*wreg[3].y;
            }
            // 16-lane DPP row sum; totals land in lane 15 (ec == 15)
            SUM16(t0); SUM16(t1); SUM16(t2); SUM16(t3);
            if (ec == 15) {
                const float dbE = bias2.x;     // dec_b[256] folded here
                *(v2f*)&plL[0][256][0] = (v2f){t0 + dbE, 0.f};
                *(v2f*)&plL[1][256][0] = (v2f){t1 + dbE, 0.f};
                *(v2f*)&plL[2][256][0] = (v2f){t2 + dbE, 0.f};
                *(v2f*)&plL[3][256][0] = (v2f){t3 + dbE, 0.f};
            }
        }
        __syncthreads();   // B2: plL(t), ghL(t+1) ready
    }
}

extern "C" void kernel_launch(void* const* d_in, const int* in_sizes, int n_in,
                              void* d_out, int out_size, void* d_ws, size_t ws_size,
                              hipStream_t stream)
{
    const int*   step        = (const int*)  d_in[0];
    const float* token_embed = (const float*)d_in[2];
    const float* step_table  = (const float*)d_in[3];
    const float* w_ih_f = (const float*)d_in[4];
    const float* w_hh_f = (const float*)d_in[5];
    const float* b_ih_f = (const float*)d_in[6];
    const float* b_hh_f = (const float*)d_in[7];
    const float* w_ih_b = (const float*)d_in[8];
    const float* w_hh_b = (const float*)d_in[9];
    const float* b_ih_b = (const float*)d_in[10];
    const float* b_hh_b = (const float*)d_in[11];
    const float* film_w = (const float*)d_in[12];
    const float* film_b = (const float*)d_in[13];
    const float* dec_w  = (const float*)d_in[14];
    const float* dec_b  = (const float*)d_in[15];
    float* ws   = (float*)d_ws;
    float* outp = (float*)d_out;

    aag_precompute<<<TOTAL_PRE / 256, 256, 0, stream>>>(
        token_embed, step_table, w_ih_f, b_ih_f, w_ih_b, b_ih_b,
        film_w, film_b, ws);
    aag_decode<<<256, 512, 0, stream>>>(
        step, w_hh_f, b_hh_f, w_hh_b, b_hh_b, dec_w, dec_b, ws, outp);
}